// Round 2
// baseline (801.035 us; speedup 1.0000x reference)
//
#include <hip/hip_runtime.h>
#include <cmath>

// AttentionBlock fused pipeline for MI355X (gfx950). Dtype-adaptive:
// probe detects fp32 vs bf16 input; compute runs in bf16 MFMA; epilogue
// honors the real dtype.
//
// B=4, C=256, N=32768, G=4 (64ch/group), NH=8, hd=32.
//
// This revision:
//  (1) 2-phase register prefetch in the GEMM K-loop (global loads for tile
//      kt+1 issued before the MFMA phase of tile kt).
//  (2) G-trick: out = M.(Wq.xhat+Bq) = (M.Wq).xhat + (M.Bq + out_b).
//      G = M.Wq stored as hi/lo bf16 planes (fp32-accurate), gamma = M.Bq+b.
//      Eliminates qT entirely; gemm1 computes only K/V; gemm2 = xt x G^T
//      with K=512 (64 MFMA between barriers).
//  (3) GN stats / beta / transpose hoisted out of the pass loop, computed
//      from raw input (xw buffer and cvt_x kernel removed). Pass memory is
//      only kv+partials -> nb=2/4 when workspace allows.

typedef __bf16 bf16x8 __attribute__((ext_vector_type(8)));
typedef float f32x4 __attribute__((ext_vector_type(4)));

union U16 { uint4 u; unsigned short s[8]; bf16x8 v; };

__device__ __forceinline__ float bf2f(unsigned short h) {
    unsigned int u = ((unsigned int)h) << 16;
    return __builtin_bit_cast(float, u);
}
__device__ __forceinline__ unsigned short f2bf(float f) {
    unsigned int u = __builtin_bit_cast(unsigned int, f);
    u = (u + 0x7fffu + ((u >> 16) & 1u)) >> 16;   // RNE
    return (unsigned short)u;
}
__device__ __forceinline__ unsigned int pack2(unsigned short a, unsigned short b) {
    return (unsigned int)a | ((unsigned int)b << 16);
}

// ------------------------------------------------------------- dtype probe
__global__ __launch_bounds__(64) void k_detect(const unsigned int* __restrict__ xr,
                                               int* __restrict__ flag) {
    unsigned int u = xr[threadIdx.x * 997];
    int e = (u >> 7) & 0xFF;
    bool ok = (e >= 100) && (e <= 141);
    unsigned long long m = __ballot(ok);
    if (threadIdx.x == 0) *flag = (__popcll(m) < 32) ? 1 : 0;   // 1 = fp32
}

// --------------------------------------------------- weight convert / copy
// wdst: qkvw[196608] | outw[65536] | gnw[256] | gnb[256] | outb[256] | wqT[65536]
__global__ __launch_bounds__(256) void k_cvt_w(const void* __restrict__ qkvw,
                                               const void* __restrict__ outw,
                                               const void* __restrict__ gnw,
                                               const void* __restrict__ gnb,
                                               const void* __restrict__ outb,
                                               const int* __restrict__ flagp,
                                               unsigned short* __restrict__ wdst) {
    int idx = blockIdx.x * 256 + threadIdx.x;
    if (idx >= 328448) return;
    int f = *flagp;
    const void* src; int off;
    if      (idx < 196608) { src = qkvw; off = idx; }
    else if (idx < 262144) { src = outw; off = idx - 196608; }
    else if (idx < 262400) { src = gnw;  off = idx - 262144; }
    else if (idx < 262656) { src = gnb;  off = idx - 262400; }
    else if (idx < 262912) { src = outb; off = idx - 262656; }
    else {  // wqT[c][d] = qkvw[d][c], q-part only (d<256)
        int i = idx - 262912;
        int c = i >> 8, d = i & 255;
        src = qkvw; off = d * 256 + c;
    }
    wdst[idx] = f ? f2bf(((const float*)src)[off])
                  : ((const unsigned short*)src)[off];
}

// ---------------------------------------------------------------- GN stats
// From raw input (fp32 or bf16). grp = b*4+g over [b][c][n] layout.
__global__ __launch_bounds__(256) void k_gnsum(const void* __restrict__ xr,
                                               const int* __restrict__ flagp,
                                               float2* __restrict__ gn_part) {
    int t = threadIdx.x, bid = blockIdx.x;
    int grp = bid >> 7, chunk = bid & 127;
    size_t base = (size_t)grp * 2097152 + (size_t)chunk * 16384;
    int f = *flagp;
    float s = 0.f, q = 0.f;
    if (f) {
        const float* p = (const float*)xr + base;
        for (int i = 0; i < 8; i++) {
            float4 a = *(const float4*)(p + i * 2048 + t * 8);
            float4 b = *(const float4*)(p + i * 2048 + t * 8 + 4);
            float v[8] = {a.x, a.y, a.z, a.w, b.x, b.y, b.z, b.w};
#pragma unroll
            for (int j = 0; j < 8; j++) { s += v[j]; q += v[j] * v[j]; }
        }
    } else {
        const unsigned short* p = (const unsigned short*)xr + base;
        for (int i = 0; i < 8; i++) {
            U16 u; u.u = *(const uint4*)(p + i * 2048 + t * 8);
#pragma unroll
            for (int j = 0; j < 8; j++) { float v = bf2f(u.s[j]); s += v; q += v * v; }
        }
    }
#pragma unroll
    for (int off = 32; off > 0; off >>= 1) { s += __shfl_xor(s, off); q += __shfl_xor(q, off); }
    __shared__ float rs[4], rq[4];
    int wave = t >> 6;
    if ((t & 63) == 0) { rs[wave] = s; rq[wave] = q; }
    __syncthreads();
    if (t == 0) gn_part[bid] = make_float2(rs[0] + rs[1] + rs[2] + rs[3],
                                           rq[0] + rq[1] + rq[2] + rq[3]);
}

__global__ __launch_bounds__(128) void k_gnfinal(const float2* __restrict__ gn_part,
                                                 float2* __restrict__ gstats) {
    int bg = blockIdx.x, t = threadIdx.x;
    float2 v = gn_part[bg * 128 + t];
    float s = v.x, q = v.y;
#pragma unroll
    for (int off = 32; off > 0; off >>= 1) { s += __shfl_xor(s, off); q += __shfl_xor(q, off); }
    __shared__ float rs[2], rq[2];
    if ((t & 63) == 0) { rs[t >> 6] = s; rq[t >> 6] = q; }
    __syncthreads();
    if (t == 0) {
        const float inv = 1.0f / 2097152.0f;
        float S = rs[0] + rs[1], Q = rq[0] + rq[1];
        float mean = S * inv;
        float var = Q * inv - mean * mean;
        gstats[bg] = make_float2(mean, rsqrtf(var + 1e-5f));
    }
}

// ---------------------------------------------------------------- beta_b[o]
__global__ __launch_bounds__(64) void k_beta(const unsigned short* __restrict__ wq,
                                             const unsigned short* __restrict__ wgnw,
                                             const unsigned short* __restrict__ wgnb,
                                             const float2* __restrict__ gstats,
                                             float* __restrict__ beta) {
    int bid = blockIdx.x;
    int b = bid / 768, o = bid % 768;
    int t = threadIdx.x, c = t * 4;
    float2 ms = gstats[b * 4 + (c >> 6)];
    uint2 qw = *(const uint2*)(wq + o * 256 + c);
    uint2 gw = *(const uint2*)(wgnw + c);
    uint2 gb = *(const uint2*)(wgnb + c);
    unsigned short qs[4] = {(unsigned short)(qw.x & 0xffff), (unsigned short)(qw.x >> 16),
                            (unsigned short)(qw.y & 0xffff), (unsigned short)(qw.y >> 16)};
    unsigned short wsx[4] = {(unsigned short)(gw.x & 0xffff), (unsigned short)(gw.x >> 16),
                             (unsigned short)(gw.y & 0xffff), (unsigned short)(gw.y >> 16)};
    unsigned short bs[4] = {(unsigned short)(gb.x & 0xffff), (unsigned short)(gb.x >> 16),
                            (unsigned short)(gb.y & 0xffff), (unsigned short)(gb.y >> 16)};
    float bacc = 0.f;
#pragma unroll
    for (int j = 0; j < 4; j++)
        bacc += bf2f(qs[j]) * (bf2f(bs[j]) - ms.x * ms.y * bf2f(wsx[j]));
#pragma unroll
    for (int off = 32; off > 0; off >>= 1) bacc += __shfl_xor(bacc, off);
    if (t == 0) beta[b * 768 + o] = bacc;
}

// --------------------------- convert + transpose + fold GN scale (raw x -> xt)
__global__ __launch_bounds__(256) void k_cvt_t(const void* __restrict__ xr,
                                               const int* __restrict__ flagp,
                                               const unsigned short* __restrict__ wgnw,
                                               const float2* __restrict__ gstats,
                                               unsigned short* __restrict__ xt) {
    int tid = threadIdx.x, bid = blockIdx.x;
    int b = bid >> 11, r2 = bid & 2047, cblk = r2 >> 9, nblk = r2 & 511;
    float rstd = gstats[b * 4 + cblk].y;
    int f = *flagp;
    __shared__ __align__(16) unsigned short T[64 * 80];
    unsigned short tmp[2][8];
#pragma unroll
    for (int i = 0; i < 2; i++) {
        int crow = (tid >> 3) + 32 * i, nch = tid & 7;
        int c = cblk * 64 + crow;
        float sc = bf2f(wgnw[c]) * rstd;
        size_t base = ((size_t)(b * 256 + c)) * 32768 + (size_t)nblk * 64 + nch * 8;
        float v[8];
        if (f) {
            float4 a = *(const float4*)((const float*)xr + base);
            float4 d = *(const float4*)((const float*)xr + base + 4);
            v[0] = a.x; v[1] = a.y; v[2] = a.z; v[3] = a.w;
            v[4] = d.x; v[5] = d.y; v[6] = d.z; v[7] = d.w;
        } else {
            U16 u; u.u = *(const uint4*)((const unsigned short*)xr + base);
#pragma unroll
            for (int j = 0; j < 8; j++) v[j] = bf2f(u.s[j]);
        }
#pragma unroll
        for (int j = 0; j < 8; j++) tmp[i][j] = f2bf(v[j] * sc);
    }
#pragma unroll
    for (int i = 0; i < 2; i++) {
        int crow = (tid >> 3) + 32 * i, nch = tid & 7;
#pragma unroll
        for (int jj = 0; jj < 8; jj++) {
            int j = (jj + tid) & 7;
            T[(nch * 8 + j) * 80 + crow] = tmp[i][j];
        }
    }
    __syncthreads();
#pragma unroll
    for (int i = 0; i < 2; i++) {
        int nrow = (tid >> 3) + 32 * i, cch = tid & 7;
        uint4 v = *(const uint4*)&T[nrow * 80 + cch * 8];
        *(uint4*)(xt + ((size_t)b * 32768 + (size_t)nblk * 64 + nrow) * 256 + cblk * 64 + cch * 8) = v;
    }
}

// ---------------------------------------------------------------- GEMM core
// LDS tile [row][64 bf16], 16B-chunk XOR swizzle: chunk c of row r at (c^(r&7)).
__device__ __forceinline__ void ld128x64(const unsigned short* __restrict__ g, int stride,
                                         int tid, uint4 (&v)[4]) {
    int wave = tid >> 6, lane = tid & 63;
    const unsigned short* gl = g + (size_t)(lane >> 3) * stride + (lane & 7) * 8;
#pragma unroll
    for (int i = 0; i < 4; i++)
        v[i] = *(const uint4*)(gl + (size_t)(wave * 32 + i * 8) * stride);
}

__device__ __forceinline__ void st128x64(unsigned short* __restrict__ lds, int tid,
                                         const uint4 (&v)[4]) {
    int wave = tid >> 6, lane = tid & 63;
#pragma unroll
    for (int i = 0; i < 4; i++) {
        int row = wave * 32 + i * 8 + (lane >> 3);
        int s = (lane & 7) ^ (row & 7);
        *(uint4*)&lds[row * 64 + s * 8] = v[i];
    }
}

__device__ __forceinline__ void mfma_tile(const unsigned short* __restrict__ ldsA,
                                          const unsigned short* __restrict__ ldsB,
                                          int l15, int quad, int wm, int wn,
                                          f32x4 (&acc)[4][4]) {
#pragma unroll
    for (int ks = 0; ks < 2; ks++) {
        bf16x8 af[4], bv[4];
#pragma unroll
        for (int mi = 0; mi < 4; mi++) {
            int row = wm * 64 + mi * 16 + l15;
            af[mi] = *(const bf16x8*)&ldsA[row * 64 + (((ks * 4 + quad) ^ (row & 7)) * 8)];
        }
#pragma unroll
        for (int ni = 0; ni < 4; ni++) {
            int row = wn * 64 + ni * 16 + l15;
            bv[ni] = *(const bf16x8*)&ldsB[row * 64 + (((ks * 4 + quad) ^ (row & 7)) * 8)];
        }
#pragma unroll
        for (int mi = 0; mi < 4; mi++)
#pragma unroll
            for (int ni = 0; ni < 4; ni++)
                acc[mi][ni] = __builtin_amdgcn_mfma_f32_16x16x32_bf16(af[mi], bv[ni], acc[mi][ni], 0, 0, 0);
    }
}

// K=256 core, both operands row-stride 256, with next-tile register prefetch.
__device__ __forceinline__ void gemm_core(const unsigned short* __restrict__ A,
                                          const unsigned short* __restrict__ B,
                                          unsigned short* ldsA, unsigned short* ldsB,
                                          int tid, f32x4 (&acc)[4][4]) {
    int lane = tid & 63, l15 = lane & 15, quad = lane >> 4;
    int wave = tid >> 6, wm = wave & 1, wn = wave >> 1;
    uint4 ra[4], rb[4];
    ld128x64(A, 256, tid, ra);
    ld128x64(B, 256, tid, rb);
    for (int kt = 0; kt < 4; kt++) {
        st128x64(ldsA, tid, ra);
        st128x64(ldsB, tid, rb);
        __syncthreads();
        if (kt < 3) {
            ld128x64(A + (kt + 1) * 64, 256, tid, ra);
            ld128x64(B + (kt + 1) * 64, 256, tid, rb);
        }
        mfma_tile(ldsA, ldsB, l15, quad, wm, wn, acc);
        __syncthreads();
    }
}

// GEMM1: kv = wq_kv . xt^T + beta  (K/V rows only; q is never materialized)
__global__ __launch_bounds__(256) void k_gemm1(const unsigned short* __restrict__ wq,
                                               const unsigned short* __restrict__ xt,
                                               const float* __restrict__ beta,
                                               unsigned short* __restrict__ kv,
                                               int b0) {
    __shared__ __align__(16) unsigned short ldsbuf[2 * 128 * 64];
    unsigned short* ldsA = ldsbuf;
    unsigned short* ldsB = ldsbuf + 128 * 64;
    int tid = threadIdx.x, bid = blockIdx.x;
    // XCD-grouped: 4 mblks sharing one xt tile consecutive on one XCD.
    int L = (bid & 7) * ((int)gridDim.x >> 3) + (bid >> 3);
    int mblk = L & 3;
    int t2 = L >> 2;
    int nblk = t2 & 255, bl = t2 >> 8;
    int gb = b0 + bl;
    int o0 = 256 + mblk * 128;           // qkv row index (k/v region)
    size_t n0 = (size_t)nblk * 128;
    const unsigned short* A = wq + (size_t)o0 * 256;
    const unsigned short* B = xt + ((size_t)gb * 32768 + n0) * 256;
    f32x4 acc[4][4] = {};
    gemm_core(A, B, ldsA, ldsB, tid, acc);

    int lane = tid & 63, l15 = lane & 15, quad = lane >> 4;
    int wave = tid >> 6, wm = wave & 1, wn = wave >> 1;
    // stage [o][n] bf16 swizzled, then full-line kv stores
#pragma unroll
    for (int mi = 0; mi < 4; mi++) {
        int o_l = wm * 64 + mi * 16 + quad * 4;
        float4 be = *(const float4*)(beta + gb * 768 + o0 + o_l);
        float bev[4] = {be.x, be.y, be.z, be.w};
#pragma unroll
        for (int ni = 0; ni < 4; ni++) {
            int n_l = wn * 64 + ni * 16 + l15;
            f32x4 v = acc[mi][ni];
#pragma unroll
            for (int r = 0; r < 4; r++) {
                int o_r = o_l + r;
                ldsbuf[(o_r * 128 + n_l) ^ ((o_r & 7) << 3)] = f2bf(v[r] + bev[r]);
            }
        }
    }
    __syncthreads();
    int kv0 = mblk * 128;
#pragma unroll
    for (int p = 0; p < 8; p++) {
        int o_r = p * 16 + (tid >> 4);
        int ch = tid & 15;
        uint4 v = *(const uint4*)&ldsbuf[(o_r * 128 + ch * 8) ^ ((o_r & 7) << 3)];
        *(uint4*)(kv + ((size_t)bl * 512 + kv0 + o_r) * 32768 + n0 + ch * 8) = v;
    }
}

// ------------------------------------------------- softmax row stats (local batch)
__global__ __launch_bounds__(256) void k_stats(const unsigned short* __restrict__ kv,
                                               float2* __restrict__ stats) {
    int row = blockIdx.x, t = threadIdx.x;
    const unsigned short* p = kv + ((size_t)(row >> 8) * 512 + (row & 255)) * 32768;
    float m = -3.0e38f;
    for (int i = 0; i < 16; i++) {
        U16 u; u.u = *(const uint4*)(p + i * 2048 + t * 8);
#pragma unroll
        for (int j = 0; j < 8; j++) m = fmaxf(m, bf2f(u.s[j]));
    }
#pragma unroll
    for (int off = 32; off > 0; off >>= 1) m = fmaxf(m, __shfl_xor(m, off));
    __shared__ float rm[4], rs[4];
    int wave = t >> 6;
    if ((t & 63) == 0) rm[wave] = m;
    __syncthreads();
    m = fmaxf(fmaxf(rm[0], rm[1]), fmaxf(rm[2], rm[3]));
    float s = 0.f;
    for (int i = 0; i < 16; i++) {
        U16 u; u.u = *(const uint4*)(p + i * 2048 + t * 8);
#pragma unroll
        for (int j = 0; j < 8; j++) s += __expf(bf2f(u.s[j]) - m);
    }
#pragma unroll
    for (int off = 32; off > 0; off >>= 1) s += __shfl_xor(s, off);
    if ((t & 63) == 0) rs[wave] = s;
    __syncthreads();
    if (t == 0) stats[row] = make_float2(m, 1.0f / (rs[0] + rs[1] + rs[2] + rs[3]));
}

// ----------------------------- sim partials (all indices pass-local)
__global__ __launch_bounds__(64) void k_sim(const unsigned short* __restrict__ kv,
                                            const float2* __restrict__ stats,
                                            float* __restrict__ partials) {
    int bid = blockIdx.x;
    int bh = bid >> 6, chunk = bid & 63;
    int b = bh >> 3, h = bh & 7;
    int lane = threadIdx.x, l15 = lane & 15, quad = lane >> 4;
    size_t n0 = (size_t)chunk * 512 + quad * 8;
    float mrow[2], isr[2];
#pragma unroll
    for (int mi = 0; mi < 2; mi++) {
        float2 st = stats[b * 256 + h * 32 + mi * 16 + l15];
        mrow[mi] = st.x; isr[mi] = st.y;
    }
    const unsigned short* kb = kv + ((size_t)b * 512 + h * 32) * 32768;
    const unsigned short* vb = kv + ((size_t)b * 512 + 256 + h * 32) * 32768;
    f32x4 acc[2][2] = {};
    for (int t = 0; t < 16; t++) {
        size_t n = n0 + t * 32;
        bf16x8 af[2], bv[2];
#pragma unroll
        for (int mi = 0; mi < 2; mi++) {
            U16 u; u.u = *(const uint4*)(kb + (size_t)(mi * 16 + l15) * 32768 + n);
            U16 pv;
#pragma unroll
            for (int j = 0; j < 8; j++) pv.s[j] = f2bf(__expf(bf2f(u.s[j]) - mrow[mi]) * isr[mi]);
            af[mi] = pv.v;
        }
#pragma unroll
        for (int ni = 0; ni < 2; ni++) {
            U16 u; u.u = *(const uint4*)(vb + (size_t)(ni * 16 + l15) * 32768 + n);
            bv[ni] = u.v;
        }
#pragma unroll
        for (int mi = 0; mi < 2; mi++)
#pragma unroll
            for (int ni = 0; ni < 2; ni++)
                acc[mi][ni] = __builtin_amdgcn_mfma_f32_16x16x32_bf16(af[mi], bv[ni], acc[mi][ni], 0, 0, 0);
    }
    float* po = partials + (size_t)(bh * 64 + chunk) * 1024;
#pragma unroll
    for (int mi = 0; mi < 2; mi++)
#pragma unroll
        for (int ni = 0; ni < 2; ni++)
#pragma unroll
            for (int rr = 0; rr < 4; rr++)
                po[(mi * 16 + quad * 4 + rr) * 32 + ni * 16 + l15] = acc[mi][ni][rr];
}

__global__ __launch_bounds__(256) void k_combine(const float* __restrict__ partials,
                                                 float* __restrict__ sim, int b0) {
    int bh = blockIdx.x, tid = threadIdx.x;
#pragma unroll
    for (int i = 0; i < 4; i++) {
        float a = 0.f;
        const float* p = partials + (size_t)bh * 65536 + tid + i * 256;
        for (int c = 0; c < 64; c++) a += p[(size_t)c * 1024];
        sim[(size_t)(b0 * 8 + bh) * 1024 + tid + i * 256] = a;
    }
}

__global__ __launch_bounds__(256) void k_buildM(const unsigned short* __restrict__ wo,
                                                const float* __restrict__ sim,
                                                unsigned short* __restrict__ M, int b0) {
    int bid = blockIdx.x, tid = threadIdx.x;
    int b = b0 + (bid >> 8), o = bid & 255;
    __shared__ float lw[256];
    __shared__ float ls[8192];
    lw[tid] = bf2f(wo[o * 256 + tid]);
#pragma unroll
    for (int i = 0; i < 32; i++) ls[tid + i * 256] = sim[(size_t)b * 8192 + tid + i * 256];
    __syncthreads();
    int h = tid >> 5, d = tid & 31;
    float a = 0.f;
#pragma unroll
    for (int e = 0; e < 32; e++) {
        int ee = (e + d) & 31;
        a += lw[h * 32 + ee] * ls[h * 1024 + d * 32 + ee];
    }
    M[((size_t)b * 256 + o) * 256 + tid] = f2bf(a);
}

// G2[b][o][0:256] = hi(M.Wq), G2[b][o][256:512] = lo  (row stride 512)
__global__ __launch_bounds__(256) void k_buildG(const unsigned short* __restrict__ M,
                                                const unsigned short* __restrict__ wqT,
                                                unsigned short* __restrict__ G2, int b0) {
    __shared__ __align__(16) unsigned short ldsbuf[2 * 128 * 64];
    unsigned short* ldsA = ldsbuf;
    unsigned short* ldsB = ldsbuf + 128 * 64;
    int tid = threadIdx.x, bid = blockIdx.x;
    int b = b0 + (bid >> 2), t = bid & 3;
    int o0 = (t >> 1) * 128, c0 = (t & 1) * 128;
    const unsigned short* A = M + (size_t)b * 65536 + (size_t)o0 * 256;   // rows o
    const unsigned short* B = wqT + (size_t)c0 * 256;                     // rows c
    f32x4 acc[4][4] = {};
    gemm_core(A, B, ldsA, ldsB, tid, acc);

    int lane = tid & 63, l15 = lane & 15, quad = lane >> 4;
    int wave = tid >> 6, wm = wave & 1, wn = wave >> 1;
#pragma unroll
    for (int mi = 0; mi < 4; mi++) {
        int o_l = o0 + wm * 64 + mi * 16 + quad * 4;
#pragma unroll
        for (int ni = 0; ni < 4; ni++) {
            int c_l = c0 + wn * 64 + ni * 16 + l15;
            f32x4 v = acc[mi][ni];
#pragma unroll
            for (int r = 0; r < 4; r++) {
                float g = v[r];
                unsigned short hi = f2bf(g);
                unsigned short lo = f2bf(g - bf2f(hi));
                size_t rb = (size_t)b * 131072 + (size_t)(o_l + r) * 512 + c_l;
                G2[rb] = hi;
                G2[rb + 256] = lo;
            }
        }
    }
}

// gamma[b][o] = sum_d M[o][d]*beta_q[b][d] + out_b[o]
__global__ __launch_bounds__(64) void k_gamma(const unsigned short* __restrict__ M,
                                              const float* __restrict__ beta,
                                              const unsigned short* __restrict__ wob,
                                              float* __restrict__ gamma, int b0) {
    int bid = blockIdx.x;
    int b = b0 + (bid >> 8), o = bid & 255;
    int t = threadIdx.x, c = t * 4;
    uint2 mw = *(const uint2*)(M + (size_t)b * 65536 + o * 256 + c);
    float4 bq = *(const float4*)(beta + b * 768 + c);
    float acc = bf2f((unsigned short)(mw.x & 0xffff)) * bq.x
              + bf2f((unsigned short)(mw.x >> 16))    * bq.y
              + bf2f((unsigned short)(mw.y & 0xffff)) * bq.z
              + bf2f((unsigned short)(mw.y >> 16))    * bq.w;
#pragma unroll
    for (int off = 32; off > 0; off >>= 1) acc += __shfl_xor(acc, off);
    if (t == 0) gamma[b * 256 + o] = acc + bf2f(wob[o]);
}

// GEMM2: out^T[n][o] = sum_{c'} xt[n][c mod 256] . G2[o][c'] + gamma + x  (K=512)
__global__ __launch_bounds__(256) void k_gemm2(const unsigned short* __restrict__ xt,
                                               const unsigned short* __restrict__ G2,
                                               const float* __restrict__ gamma,
                                               const void* __restrict__ xr,
                                               const int* __restrict__ flagp,
                                               void* __restrict__ outv,
                                               int b0) {
    __shared__ __align__(16) unsigned short ldsbuf[2 * 128 * 64];
    unsigned short* ldsA = ldsbuf;
    unsigned short* ldsB = ldsbuf + 128 * 64;
    float* ldsF = (float*)ldsbuf;
    int tid = threadIdx.x, bid = blockIdx.x;
    // XCD-grouped: the 2 oblks sharing one xt tile consecutive on one XCD.
    int L = (bid & 7) * ((int)gridDim.x >> 3) + (bid >> 3);
    int oblk = L & 1;
    int t2 = L >> 1;
    int mblk = t2 & 255, bl = t2 >> 8;
    int gb = b0 + bl;
    size_t n0 = (size_t)mblk * 128;
    int o0 = oblk * 128;
    const unsigned short* A = xt + ((size_t)gb * 32768 + n0) * 256;
    const unsigned short* Bg = G2 + (size_t)gb * 131072 + (size_t)o0 * 512;

    int lane = tid & 63, l15 = lane & 15, quad = lane >> 4;
    int wave = tid >> 6, wm = wave & 1, wn = wave >> 1;
    f32x4 acc[4][4] = {};
    uint4 ra[4], rb[4];
    ld128x64(A, 256, tid, ra);
    ld128x64(Bg, 512, tid, rb);
    for (int kt = 0; kt < 8; kt++) {
        st128x64(ldsA, tid, ra);
        st128x64(ldsB, tid, rb);
        __syncthreads();
        if (kt < 7) {
            ld128x64(A + ((kt + 1) & 3) * 64, 256, tid, ra);
            ld128x64(Bg + (kt + 1) * 64, 512, tid, rb);
        }
        mfma_tile(ldsA, ldsB, l15, quad, wm, wn, acc);
        __syncthreads();
    }

    int f = *flagp;
    // acc rows = n-local (mi,quad,reg), cols = o-local (ni,l15).
    // Two half-passes over o: stage fp32 [o_h][n] (32KB) swizzled, then
    // cooperative residual + full-line store in [o][n].
    for (int half = 0; half < 2; half++) {
        if (wn == half) {
#pragma unroll
            for (int mi = 0; mi < 4; mi++) {
#pragma unroll
                for (int ni = 0; ni < 4; ni++) {
                    int o_h = ni * 16 + l15;
                    f32x4 v = acc[mi][ni];
#pragma unroll
                    for (int r = 0; r < 4; r++) {
                        int n_l = wm * 64 + mi * 16 + quad * 4 + r;
                        ldsF[(o_h * 128 + n_l) ^ ((o_h & 15) << 2)] = v[r];
                    }
                }
            }
        }
        __syncthreads();
#pragma unroll
        for (int p = 0; p < 8; p++) {
            int o_h = p * 8 + (tid >> 5);
            int ch = tid & 31;
            float4 v = *(const float4*)&ldsF[(o_h * 128 + ch * 4) ^ ((o_h & 15) << 2)];
            int o = o0 + half * 64 + o_h;
            float bias = gamma[gb * 256 + o];
            size_t base = ((size_t)gb * 256 + o) * 32768 + n0 + ch * 4;
            if (f) {
                float4 xv = *(const float4*)((const float*)xr + base);
                float4 ov = make_float4(v.x + bias + xv.x, v.y + bias + xv.y,
                                        v.z + bias + xv.z, v.w + bias + xv.w);
                *(float4*)((float*)outv + base) = ov;
            } else {
                uint2 xr2 = *(const uint2*)((const unsigned short*)xr + base);
                unsigned short xs[4] = {(unsigned short)(xr2.x & 0xffff), (unsigned short)(xr2.x >> 16),
                                        (unsigned short)(xr2.y & 0xffff), (unsigned short)(xr2.y >> 16)};
                uint2 pv;
                pv.x = pack2(f2bf(v.x + bias + bf2f(xs[0])), f2bf(v.y + bias + bf2f(xs[1])));
                pv.y = pack2(f2bf(v.z + bias + bf2f(xs[2])), f2bf(v.w + bias + bf2f(xs[3])));
                *(uint2*)((unsigned short*)outv + base) = pv;
            }
        }
        __syncthreads();
    }
}

extern "C" void kernel_launch(void* const* d_in, const int* in_sizes, int n_in,
                              void* d_out, int out_size, void* d_ws, size_t ws_size,
                              hipStream_t stream) {
    const void* x    = d_in[0];
    const void* gnw  = d_in[1];
    const void* gnb  = d_in[2];
    const void* qkvw = d_in[3];
    const void* outw = d_in[4];
    const void* outb = d_in[5];
    char* ws = (char*)d_ws;

    // ---- workspace layout
    unsigned short* xt   = (unsigned short*)(ws);              // 64 MiB, [b][n][c]
    unsigned short* wdst = (unsigned short*)(ws + 67108864);   // 656896 B
    char* sm = ws + 68157440;
    int*    flag    = (int*)(sm);
    float2* gstats  = (float2*)(sm + 64);
    float*  beta    = (float*)(sm + 1024);      // 4*768 f32
    float2* stats   = (float2*)(sm + 16384);    // nb*256 f2 (pass-local)
    float*  gamma   = (float*)(sm + 24576);     // 4*256 f32
    float2* gn_part = (float2*)(sm + 32768);    // 2048 f2
    float*  sim     = (float*)(sm + 65536);     // 4*8*1024 f32
    unsigned short* M  = (unsigned short*)(sm + 262144);  // 4*256*256 bf16
    unsigned short* G2 = (unsigned short*)(sm + 786432);  // 4*256*512 bf16
    const size_t kv_off = 70254592;

    const unsigned short* wq   = wdst;
    const unsigned short* wo   = wdst + 196608;
    const unsigned short* wgnw = wdst + 262144;
    const unsigned short* wgnb = wdst + 262400;
    const unsigned short* wob  = wdst + 262656;
    const unsigned short* wqT  = wdst + 262912;

    int nb = 1;
    if      (ws_size >= kv_off + 4ull * (33554432 + 2097152)) nb = 4;
    else if (ws_size >= kv_off + 2ull * (33554432 + 2097152)) nb = 2;

    unsigned short* kv = (unsigned short*)(ws + kv_off);
    float* partials    = (float*)(ws + kv_off + (size_t)nb * 33554432);

    k_detect <<<dim3(1),    dim3(64),  0, stream>>>((const unsigned int*)x, flag);
    k_cvt_w  <<<dim3(1283), dim3(256), 0, stream>>>(qkvw, outw, gnw, gnb, outb, flag, wdst);
    k_gnsum  <<<dim3(2048), dim3(256), 0, stream>>>(x, flag, gn_part);
    k_gnfinal<<<dim3(16),   dim3(128), 0, stream>>>(gn_part, gstats);
    k_beta   <<<dim3(3072), dim3(64),  0, stream>>>(wq, wgnw, wgnb, gstats, beta);
    k_cvt_t  <<<dim3(8192), dim3(256), 0, stream>>>(x, flag, wgnw, gstats, xt);

    for (int pass = 0; pass < 4; pass += nb) {
        k_gemm1  <<<dim3(1024 * nb), dim3(256), 0, stream>>>(wq, xt, beta, kv, pass);
        k_stats  <<<dim3(256 * nb),  dim3(256), 0, stream>>>(kv, stats);
        k_sim    <<<dim3(512 * nb),  dim3(64),  0, stream>>>(kv, stats, partials);
        k_combine<<<dim3(8 * nb),    dim3(256), 0, stream>>>(partials, sim, pass);
        k_buildM <<<dim3(256 * nb),  dim3(256), 0, stream>>>(wo, sim, M, pass);
        k_buildG <<<dim3(4 * nb),    dim3(256), 0, stream>>>(M, wqT, G2, pass);
        k_gamma  <<<dim3(256 * nb),  dim3(64),  0, stream>>>(M, beta, wob, gamma, pass);
        k_gemm2  <<<dim3(512 * nb),  dim3(256), 0, stream>>>(xt, G2, gamma, x, flag, d_out, pass);
    }
}

// Round 3
// 520.298 us; speedup vs baseline: 1.5396x; 1.5396x over previous
//
#include <hip/hip_runtime.h>
#include <cmath>

// AttentionBlock fused pipeline for MI355X (gfx950). Dtype-adaptive:
// probe detects fp32 vs bf16 input; compute runs in bf16 MFMA; epilogue
// honors the real dtype.
//
// B=4, C=256, N=32768, G=4 (64ch/group), NH=8, hd=32.
//
// This revision:
//  (1) m97-style staging: __builtin_amdgcn_global_load_lds width=16 in all
//      GEMM cores (no VGPR round-trip, deep VMEM pipeline). LDS dest is
//      linear; the XOR chunk-swizzle is baked into the per-lane GLOBAL
//      source address; ds_read side swizzled as before.
//  (2) k_gemm2 hoisted out of the pass loop (depends only on persistent
//      xt/G2/gamma): one launch, grid 2048, better occupancy and tail.
//  (3) k_gamma folded into k_buildM (block-reduce over the M row).

typedef __bf16 bf16x8 __attribute__((ext_vector_type(8)));
typedef float f32x4 __attribute__((ext_vector_type(4)));

union U16 { uint4 u; unsigned short s[8]; bf16x8 v; };

__device__ __forceinline__ float bf2f(unsigned short h) {
    unsigned int u = ((unsigned int)h) << 16;
    return __builtin_bit_cast(float, u);
}
__device__ __forceinline__ unsigned short f2bf(float f) {
    unsigned int u = __builtin_bit_cast(unsigned int, f);
    u = (u + 0x7fffu + ((u >> 16) & 1u)) >> 16;   // RNE
    return (unsigned short)u;
}
__device__ __forceinline__ unsigned int pack2(unsigned short a, unsigned short b) {
    return (unsigned int)a | ((unsigned int)b << 16);
}

// ------------------------------------------------------------- dtype probe
__global__ __launch_bounds__(64) void k_detect(const unsigned int* __restrict__ xr,
                                               int* __restrict__ flag) {
    unsigned int u = xr[threadIdx.x * 997];
    int e = (u >> 7) & 0xFF;
    bool ok = (e >= 100) && (e <= 141);
    unsigned long long m = __ballot(ok);
    if (threadIdx.x == 0) *flag = (__popcll(m) < 32) ? 1 : 0;   // 1 = fp32
}

// --------------------------------------------------- weight convert / copy
// wdst: qkvw[196608] | outw[65536] | gnw[256] | gnb[256] | outb[256] | wqT[65536]
__global__ __launch_bounds__(256) void k_cvt_w(const void* __restrict__ qkvw,
                                               const void* __restrict__ outw,
                                               const void* __restrict__ gnw,
                                               const void* __restrict__ gnb,
                                               const void* __restrict__ outb,
                                               const int* __restrict__ flagp,
                                               unsigned short* __restrict__ wdst) {
    int idx = blockIdx.x * 256 + threadIdx.x;
    if (idx >= 328448) return;
    int f = *flagp;
    const void* src; int off;
    if      (idx < 196608) { src = qkvw; off = idx; }
    else if (idx < 262144) { src = outw; off = idx - 196608; }
    else if (idx < 262400) { src = gnw;  off = idx - 262144; }
    else if (idx < 262656) { src = gnb;  off = idx - 262400; }
    else if (idx < 262912) { src = outb; off = idx - 262656; }
    else {  // wqT[c][d] = qkvw[d][c], q-part only (d<256)
        int i = idx - 262912;
        int c = i >> 8, d = i & 255;
        src = qkvw; off = d * 256 + c;
    }
    wdst[idx] = f ? f2bf(((const float*)src)[off])
                  : ((const unsigned short*)src)[off];
}

// ---------------------------------------------------------------- GN stats
__global__ __launch_bounds__(256) void k_gnsum(const void* __restrict__ xr,
                                               const int* __restrict__ flagp,
                                               float2* __restrict__ gn_part) {
    int t = threadIdx.x, bid = blockIdx.x;
    int grp = bid >> 7, chunk = bid & 127;
    size_t base = (size_t)grp * 2097152 + (size_t)chunk * 16384;
    int f = *flagp;
    float s = 0.f, q = 0.f;
    if (f) {
        const float* p = (const float*)xr + base;
        for (int i = 0; i < 8; i++) {
            float4 a = *(const float4*)(p + i * 2048 + t * 8);
            float4 b = *(const float4*)(p + i * 2048 + t * 8 + 4);
            float v[8] = {a.x, a.y, a.z, a.w, b.x, b.y, b.z, b.w};
#pragma unroll
            for (int j = 0; j < 8; j++) { s += v[j]; q += v[j] * v[j]; }
        }
    } else {
        const unsigned short* p = (const unsigned short*)xr + base;
        for (int i = 0; i < 8; i++) {
            U16 u; u.u = *(const uint4*)(p + i * 2048 + t * 8);
#pragma unroll
            for (int j = 0; j < 8; j++) { float v = bf2f(u.s[j]); s += v; q += v * v; }
        }
    }
#pragma unroll
    for (int off = 32; off > 0; off >>= 1) { s += __shfl_xor(s, off); q += __shfl_xor(q, off); }
    __shared__ float rs[4], rq[4];
    int wave = t >> 6;
    if ((t & 63) == 0) { rs[wave] = s; rq[wave] = q; }
    __syncthreads();
    if (t == 0) gn_part[bid] = make_float2(rs[0] + rs[1] + rs[2] + rs[3],
                                           rq[0] + rq[1] + rq[2] + rq[3]);
}

__global__ __launch_bounds__(128) void k_gnfinal(const float2* __restrict__ gn_part,
                                                 float2* __restrict__ gstats) {
    int bg = blockIdx.x, t = threadIdx.x;
    float2 v = gn_part[bg * 128 + t];
    float s = v.x, q = v.y;
#pragma unroll
    for (int off = 32; off > 0; off >>= 1) { s += __shfl_xor(s, off); q += __shfl_xor(q, off); }
    __shared__ float rs[2], rq[2];
    if ((t & 63) == 0) { rs[t >> 6] = s; rq[t >> 6] = q; }
    __syncthreads();
    if (t == 0) {
        const float inv = 1.0f / 2097152.0f;
        float S = rs[0] + rs[1], Q = rq[0] + rq[1];
        float mean = S * inv;
        float var = Q * inv - mean * mean;
        gstats[bg] = make_float2(mean, rsqrtf(var + 1e-5f));
    }
}

// ---------------------------------------------------------------- beta_b[o]
__global__ __launch_bounds__(64) void k_beta(const unsigned short* __restrict__ wq,
                                             const unsigned short* __restrict__ wgnw,
                                             const unsigned short* __restrict__ wgnb,
                                             const float2* __restrict__ gstats,
                                             float* __restrict__ beta) {
    int bid = blockIdx.x;
    int b = bid / 768, o = bid % 768;
    int t = threadIdx.x, c = t * 4;
    float2 ms = gstats[b * 4 + (c >> 6)];
    uint2 qw = *(const uint2*)(wq + o * 256 + c);
    uint2 gw = *(const uint2*)(wgnw + c);
    uint2 gb = *(const uint2*)(wgnb + c);
    unsigned short qs[4] = {(unsigned short)(qw.x & 0xffff), (unsigned short)(qw.x >> 16),
                            (unsigned short)(qw.y & 0xffff), (unsigned short)(qw.y >> 16)};
    unsigned short wsx[4] = {(unsigned short)(gw.x & 0xffff), (unsigned short)(gw.x >> 16),
                             (unsigned short)(gw.y & 0xffff), (unsigned short)(gw.y >> 16)};
    unsigned short bs[4] = {(unsigned short)(gb.x & 0xffff), (unsigned short)(gb.x >> 16),
                            (unsigned short)(gb.y & 0xffff), (unsigned short)(gb.y >> 16)};
    float bacc = 0.f;
#pragma unroll
    for (int j = 0; j < 4; j++)
        bacc += bf2f(qs[j]) * (bf2f(bs[j]) - ms.x * ms.y * bf2f(wsx[j]));
#pragma unroll
    for (int off = 32; off > 0; off >>= 1) bacc += __shfl_xor(bacc, off);
    if (t == 0) beta[b * 768 + o] = bacc;
}

// --------------------------- convert + transpose + fold GN scale (raw x -> xt)
__global__ __launch_bounds__(256) void k_cvt_t(const void* __restrict__ xr,
                                               const int* __restrict__ flagp,
                                               const unsigned short* __restrict__ wgnw,
                                               const float2* __restrict__ gstats,
                                               unsigned short* __restrict__ xt) {
    int tid = threadIdx.x, bid = blockIdx.x;
    int b = bid >> 11, r2 = bid & 2047, cblk = r2 >> 9, nblk = r2 & 511;
    float rstd = gstats[b * 4 + cblk].y;
    int f = *flagp;
    __shared__ __align__(16) unsigned short T[64 * 80];
    unsigned short tmp[2][8];
#pragma unroll
    for (int i = 0; i < 2; i++) {
        int crow = (tid >> 3) + 32 * i, nch = tid & 7;
        int c = cblk * 64 + crow;
        float sc = bf2f(wgnw[c]) * rstd;
        size_t base = ((size_t)(b * 256 + c)) * 32768 + (size_t)nblk * 64 + nch * 8;
        float v[8];
        if (f) {
            float4 a = *(const float4*)((const float*)xr + base);
            float4 d = *(const float4*)((const float*)xr + base + 4);
            v[0] = a.x; v[1] = a.y; v[2] = a.z; v[3] = a.w;
            v[4] = d.x; v[5] = d.y; v[6] = d.z; v[7] = d.w;
        } else {
            U16 u; u.u = *(const uint4*)((const unsigned short*)xr + base);
#pragma unroll
            for (int j = 0; j < 8; j++) v[j] = bf2f(u.s[j]);
        }
#pragma unroll
        for (int j = 0; j < 8; j++) tmp[i][j] = f2bf(v[j] * sc);
    }
#pragma unroll
    for (int i = 0; i < 2; i++) {
        int crow = (tid >> 3) + 32 * i, nch = tid & 7;
#pragma unroll
        for (int jj = 0; jj < 8; jj++) {
            int j = (jj + tid) & 7;
            T[(nch * 8 + j) * 80 + crow] = tmp[i][j];
        }
    }
    __syncthreads();
#pragma unroll
    for (int i = 0; i < 2; i++) {
        int nrow = (tid >> 3) + 32 * i, cch = tid & 7;
        uint4 v = *(const uint4*)&T[nrow * 80 + cch * 8];
        *(uint4*)(xt + ((size_t)b * 32768 + (size_t)nblk * 64 + nrow) * 256 + cblk * 64 + cch * 8) = v;
    }
}

// ---------------------------------------------------------------- GEMM core
// LDS tile [row][64 bf16], LINEAR layout fed by global_load_lds; the XOR
// chunk swizzle (logical chunk c of row r lives at slot c^(r&7)) is applied
// on the per-lane GLOBAL source address; ds_read applies the same XOR.
__device__ __forceinline__ void stage_tile(const unsigned short* __restrict__ g, int stride,
                                           unsigned short* __restrict__ lds, int tid) {
    int lane = tid & 63, wave = tid >> 6;
    int r8 = lane >> 3, s = lane & 7;
#pragma unroll
    for (int i = 0; i < 4; i++) {
        int row0 = wave * 32 + i * 8;
        int row = row0 + r8;
        const unsigned short* src = g + (size_t)row * stride + ((s ^ (row & 7)) << 3);
        // lane l of the wave writes lds_base + l*16 (HW-linear); src is per-lane.
        __builtin_amdgcn_global_load_lds(
            (__attribute__((address_space(1))) void*)src,
            (__attribute__((address_space(3))) void*)(lds + row0 * 64),
            16, 0, 0);
    }
}

__device__ __forceinline__ void mfma_tile(const unsigned short* __restrict__ ldsA,
                                          const unsigned short* __restrict__ ldsB,
                                          int l15, int quad, int wm, int wn,
                                          f32x4 (&acc)[4][4]) {
#pragma unroll
    for (int ks = 0; ks < 2; ks++) {
        bf16x8 af[4], bv[4];
#pragma unroll
        for (int mi = 0; mi < 4; mi++) {
            int row = wm * 64 + mi * 16 + l15;
            af[mi] = *(const bf16x8*)&ldsA[row * 64 + (((ks * 4 + quad) ^ (row & 7)) * 8)];
        }
#pragma unroll
        for (int ni = 0; ni < 4; ni++) {
            int row = wn * 64 + ni * 16 + l15;
            bv[ni] = *(const bf16x8*)&ldsB[row * 64 + (((ks * 4 + quad) ^ (row & 7)) * 8)];
        }
#pragma unroll
        for (int mi = 0; mi < 4; mi++)
#pragma unroll
            for (int ni = 0; ni < 4; ni++)
                acc[mi][ni] = __builtin_amdgcn_mfma_f32_16x16x32_bf16(af[mi], bv[ni], acc[mi][ni], 0, 0, 0);
    }
}

// K-loop: KSTEPS 64-wide K tiles; A tile index wraps at KAMASK+1.
template<int KSTEPS, int KAMASK>
__device__ __forceinline__ void gemm_core_g(const unsigned short* __restrict__ A, int strideA,
                                            const unsigned short* __restrict__ B, int strideB,
                                            unsigned short* ldsA, unsigned short* ldsB,
                                            int tid, f32x4 (&acc)[4][4]) {
    int lane = tid & 63, l15 = lane & 15, quad = lane >> 4;
    int wave = tid >> 6, wm = wave & 1, wn = wave >> 1;
#pragma unroll
    for (int kt = 0; kt < KSTEPS; kt++) {
        stage_tile(A + (kt & KAMASK) * 64, strideA, ldsA, tid);
        stage_tile(B + kt * 64, strideB, ldsB, tid);
        __syncthreads();           // compiler emits vmcnt(0) drain + barrier
        mfma_tile(ldsA, ldsB, l15, quad, wm, wn, acc);
        __syncthreads();
    }
}

// GEMM1: kv = wq_kv . xt^T + beta  (K/V rows only; q never materialized)
__global__ __launch_bounds__(256) void k_gemm1(const unsigned short* __restrict__ wq,
                                               const unsigned short* __restrict__ xt,
                                               const float* __restrict__ beta,
                                               unsigned short* __restrict__ kv,
                                               int b0) {
    __shared__ __align__(16) unsigned short ldsbuf[2 * 128 * 64];
    unsigned short* ldsA = ldsbuf;
    unsigned short* ldsB = ldsbuf + 128 * 64;
    int tid = threadIdx.x, bid = blockIdx.x;
    // XCD-grouped: 4 mblks sharing one xt tile consecutive on one XCD.
    int L = (bid & 7) * ((int)gridDim.x >> 3) + (bid >> 3);
    int mblk = L & 3;
    int t2 = L >> 2;
    int nblk = t2 & 255, bl = t2 >> 8;
    int gb = b0 + bl;
    int o0 = 256 + mblk * 128;           // qkv row index (k/v region)
    size_t n0 = (size_t)nblk * 128;
    const unsigned short* A = wq + (size_t)o0 * 256;
    const unsigned short* B = xt + ((size_t)gb * 32768 + n0) * 256;
    f32x4 acc[4][4] = {};
    gemm_core_g<4, 3>(A, 256, B, 256, ldsA, ldsB, tid, acc);

    int lane = tid & 63, l15 = lane & 15, quad = lane >> 4;
    int wave = tid >> 6, wm = wave & 1, wn = wave >> 1;
    // stage [o][n] bf16 swizzled in LDS, then full-line kv stores
#pragma unroll
    for (int mi = 0; mi < 4; mi++) {
        int o_l = wm * 64 + mi * 16 + quad * 4;
        float4 be = *(const float4*)(beta + gb * 768 + o0 + o_l);
        float bev[4] = {be.x, be.y, be.z, be.w};
#pragma unroll
        for (int ni = 0; ni < 4; ni++) {
            int n_l = wn * 64 + ni * 16 + l15;
            f32x4 v = acc[mi][ni];
#pragma unroll
            for (int r = 0; r < 4; r++) {
                int o_r = o_l + r;
                ldsbuf[(o_r * 128 + n_l) ^ ((o_r & 7) << 3)] = f2bf(v[r] + bev[r]);
            }
        }
    }
    __syncthreads();
    int kv0 = mblk * 128;
#pragma unroll
    for (int p = 0; p < 8; p++) {
        int o_r = p * 16 + (tid >> 4);
        int ch = tid & 15;
        uint4 v = *(const uint4*)&ldsbuf[(o_r * 128 + ch * 8) ^ ((o_r & 7) << 3)];
        *(uint4*)(kv + ((size_t)bl * 512 + kv0 + o_r) * 32768 + n0 + ch * 8) = v;
    }
}

// ------------------------------------------------- softmax row stats (pass-local)
__global__ __launch_bounds__(256) void k_stats(const unsigned short* __restrict__ kv,
                                               float2* __restrict__ stats) {
    int row = blockIdx.x, t = threadIdx.x;
    const unsigned short* p = kv + ((size_t)(row >> 8) * 512 + (row & 255)) * 32768;
    float m = -3.0e38f;
    for (int i = 0; i < 16; i++) {
        U16 u; u.u = *(const uint4*)(p + i * 2048 + t * 8);
#pragma unroll
        for (int j = 0; j < 8; j++) m = fmaxf(m, bf2f(u.s[j]));
    }
#pragma unroll
    for (int off = 32; off > 0; off >>= 1) m = fmaxf(m, __shfl_xor(m, off));
    __shared__ float rm[4], rs[4];
    int wave = t >> 6;
    if ((t & 63) == 0) rm[wave] = m;
    __syncthreads();
    m = fmaxf(fmaxf(rm[0], rm[1]), fmaxf(rm[2], rm[3]));
    float s = 0.f;
    for (int i = 0; i < 16; i++) {
        U16 u; u.u = *(const uint4*)(p + i * 2048 + t * 8);
#pragma unroll
        for (int j = 0; j < 8; j++) s += __expf(bf2f(u.s[j]) - m);
    }
#pragma unroll
    for (int off = 32; off > 0; off >>= 1) s += __shfl_xor(s, off);
    if ((t & 63) == 0) rs[wave] = s;
    __syncthreads();
    if (t == 0) stats[row] = make_float2(m, 1.0f / (rs[0] + rs[1] + rs[2] + rs[3]));
}

// ----------------------------- sim partials (pass-local)
__global__ __launch_bounds__(64) void k_sim(const unsigned short* __restrict__ kv,
                                            const float2* __restrict__ stats,
                                            float* __restrict__ partials) {
    int bid = blockIdx.x;
    int bh = bid >> 6, chunk = bid & 63;
    int b = bh >> 3, h = bh & 7;
    int lane = threadIdx.x, l15 = lane & 15, quad = lane >> 4;
    size_t n0 = (size_t)chunk * 512 + quad * 8;
    float mrow[2], isr[2];
#pragma unroll
    for (int mi = 0; mi < 2; mi++) {
        float2 st = stats[b * 256 + h * 32 + mi * 16 + l15];
        mrow[mi] = st.x; isr[mi] = st.y;
    }
    const unsigned short* kb = kv + ((size_t)b * 512 + h * 32) * 32768;
    const unsigned short* vb = kv + ((size_t)b * 512 + 256 + h * 32) * 32768;
    f32x4 acc[2][2] = {};
    for (int t = 0; t < 16; t++) {
        size_t n = n0 + t * 32;
        bf16x8 af[2], bv[2];
#pragma unroll
        for (int mi = 0; mi < 2; mi++) {
            U16 u; u.u = *(const uint4*)(kb + (size_t)(mi * 16 + l15) * 32768 + n);
            U16 pv;
#pragma unroll
            for (int j = 0; j < 8; j++) pv.s[j] = f2bf(__expf(bf2f(u.s[j]) - mrow[mi]) * isr[mi]);
            af[mi] = pv.v;
        }
#pragma unroll
        for (int ni = 0; ni < 2; ni++) {
            U16 u; u.u = *(const uint4*)(vb + (size_t)(ni * 16 + l15) * 32768 + n);
            bv[ni] = u.v;
        }
#pragma unroll
        for (int mi = 0; mi < 2; mi++)
#pragma unroll
            for (int ni = 0; ni < 2; ni++)
                acc[mi][ni] = __builtin_amdgcn_mfma_f32_16x16x32_bf16(af[mi], bv[ni], acc[mi][ni], 0, 0, 0);
    }
    float* po = partials + (size_t)(bh * 64 + chunk) * 1024;
#pragma unroll
    for (int mi = 0; mi < 2; mi++)
#pragma unroll
        for (int ni = 0; ni < 2; ni++)
#pragma unroll
            for (int rr = 0; rr < 4; rr++)
                po[(mi * 16 + quad * 4 + rr) * 32 + ni * 16 + l15] = acc[mi][ni][rr];
}

__global__ __launch_bounds__(256) void k_combine(const float* __restrict__ partials,
                                                 float* __restrict__ sim, int b0) {
    int bh = blockIdx.x, tid = threadIdx.x;
#pragma unroll
    for (int i = 0; i < 4; i++) {
        float a = 0.f;
        const float* p = partials + (size_t)bh * 65536 + tid + i * 256;
        for (int c = 0; c < 64; c++) a += p[(size_t)c * 1024];
        sim[(size_t)(b0 * 8 + bh) * 1024 + tid + i * 256] = a;
    }
}

// buildM + folded gamma: M[b][o][c] and gamma[b][o] = M.beta_q + out_b
__global__ __launch_bounds__(256) void k_buildM(const unsigned short* __restrict__ wo,
                                                const float* __restrict__ sim,
                                                const float* __restrict__ beta,
                                                const unsigned short* __restrict__ wob,
                                                unsigned short* __restrict__ M,
                                                float* __restrict__ gamma, int b0) {
    int bid = blockIdx.x, tid = threadIdx.x;
    int b = b0 + (bid >> 8), o = bid & 255;
    __shared__ float lw[256];
    __shared__ float ls[8192];
    lw[tid] = bf2f(wo[o * 256 + tid]);
#pragma unroll
    for (int i = 0; i < 32; i++) ls[tid + i * 256] = sim[(size_t)b * 8192 + tid + i * 256];
    __syncthreads();
    int h = tid >> 5, d = tid & 31;
    float a = 0.f;
#pragma unroll
    for (int e = 0; e < 32; e++) {
        int ee = (e + d) & 31;
        a += lw[h * 32 + ee] * ls[h * 1024 + d * 32 + ee];
    }
    unsigned short mh = f2bf(a);
    M[((size_t)b * 256 + o) * 256 + tid] = mh;
    // gamma[b][o] = sum_c M[o][c] * beta_q[b][c]  (+ out_b)
    float g = bf2f(mh) * beta[b * 768 + tid];
#pragma unroll
    for (int off = 32; off > 0; off >>= 1) g += __shfl_xor(g, off);
    __shared__ float rg[4];
    if ((tid & 63) == 0) rg[tid >> 6] = g;
    __syncthreads();
    if (tid == 0) gamma[b * 256 + o] = rg[0] + rg[1] + rg[2] + rg[3] + bf2f(wob[o]);
}

// G2[b][o][0:256] = hi(M.Wq), G2[b][o][256:512] = lo  (row stride 512)
__global__ __launch_bounds__(256) void k_buildG(const unsigned short* __restrict__ M,
                                                const unsigned short* __restrict__ wqT,
                                                unsigned short* __restrict__ G2, int b0) {
    __shared__ __align__(16) unsigned short ldsbuf[2 * 128 * 64];
    unsigned short* ldsA = ldsbuf;
    unsigned short* ldsB = ldsbuf + 128 * 64;
    int tid = threadIdx.x, bid = blockIdx.x;
    int b = b0 + (bid >> 2), t = bid & 3;
    int o0 = (t >> 1) * 128, c0 = (t & 1) * 128;
    const unsigned short* A = M + (size_t)b * 65536 + (size_t)o0 * 256;   // rows o
    const unsigned short* B = wqT + (size_t)c0 * 256;                     // rows c
    f32x4 acc[4][4] = {};
    gemm_core_g<4, 3>(A, 256, B, 256, ldsA, ldsB, tid, acc);

    int lane = tid & 63, l15 = lane & 15, quad = lane >> 4;
    int wave = tid >> 6, wm = wave & 1, wn = wave >> 1;
#pragma unroll
    for (int mi = 0; mi < 4; mi++) {
        int o_l = o0 + wm * 64 + mi * 16 + quad * 4;
#pragma unroll
        for (int ni = 0; ni < 4; ni++) {
            int c_l = c0 + wn * 64 + ni * 16 + l15;
            f32x4 v = acc[mi][ni];
#pragma unroll
            for (int r = 0; r < 4; r++) {
                float g = v[r];
                unsigned short hi = f2bf(g);
                unsigned short lo = f2bf(g - bf2f(hi));
                size_t rb = (size_t)b * 131072 + (size_t)(o_l + r) * 512 + c_l;
                G2[rb] = hi;
                G2[rb + 256] = lo;
            }
        }
    }
}

// GEMM2 (all batches): out[b][o][n] = xt[n][.] . G2[o][.] + gamma + x  (K=512)
__global__ __launch_bounds__(256) void k_gemm2(const unsigned short* __restrict__ xt,
                                               const unsigned short* __restrict__ G2,
                                               const float* __restrict__ gamma,
                                               const void* __restrict__ xr,
                                               const int* __restrict__ flagp,
                                               void* __restrict__ outv) {
    __shared__ __align__(16) unsigned short ldsbuf[2 * 128 * 64];
    unsigned short* ldsA = ldsbuf;
    unsigned short* ldsB = ldsbuf + 128 * 64;
    float* ldsF = (float*)ldsbuf;
    int tid = threadIdx.x, bid = blockIdx.x;
    // XCD-grouped: 2 oblks sharing one xt tile consecutive on one XCD.
    int L = (bid & 7) * ((int)gridDim.x >> 3) + (bid >> 3);
    int oblk = L & 1;
    int mblk = (L >> 1) & 255;
    int b = L >> 9;
    size_t n0 = (size_t)mblk * 128;
    int o0 = oblk * 128;
    const unsigned short* A = xt + ((size_t)b * 32768 + n0) * 256;
    const unsigned short* Bg = G2 + (size_t)b * 131072 + (size_t)o0 * 512;
    f32x4 acc[4][4] = {};
    gemm_core_g<8, 3>(A, 256, Bg, 512, ldsA, ldsB, tid, acc);

    int f = *flagp;
    int lane = tid & 63, l15 = lane & 15, quad = lane >> 4;
    int wave = tid >> 6, wm = wave & 1, wn = wave >> 1;
    // acc rows = n-local (mi,quad,reg), cols = o-local (ni,l15).
    // Two half-passes over o: stage fp32 [o_h][n] (32KB) swizzled, then
    // cooperative residual + full-line store in [o][n].
    for (int half = 0; half < 2; half++) {
        if (wn == half) {
#pragma unroll
            for (int mi = 0; mi < 4; mi++) {
#pragma unroll
                for (int ni = 0; ni < 4; ni++) {
                    int o_h = ni * 16 + l15;
                    f32x4 v = acc[mi][ni];
#pragma unroll
                    for (int r = 0; r < 4; r++) {
                        int n_l = wm * 64 + mi * 16 + quad * 4 + r;
                        ldsF[(o_h * 128 + n_l) ^ ((o_h & 15) << 2)] = v[r];
                    }
                }
            }
        }
        __syncthreads();
#pragma unroll
        for (int p = 0; p < 8; p++) {
            int o_h = p * 8 + (tid >> 5);
            int ch = tid & 31;
            float4 v = *(const float4*)&ldsF[(o_h * 128 + ch * 4) ^ ((o_h & 15) << 2)];
            int o = o0 + half * 64 + o_h;
            float bias = gamma[b * 256 + o];
            size_t base = ((size_t)b * 256 + o) * 32768 + n0 + ch * 4;
            if (f) {
                float4 xv = *(const float4*)((const float*)xr + base);
                float4 ov = make_float4(v.x + bias + xv.x, v.y + bias + xv.y,
                                        v.z + bias + xv.z, v.w + bias + xv.w);
                *(float4*)((float*)outv + base) = ov;
            } else {
                uint2 xr2 = *(const uint2*)((const unsigned short*)xr + base);
                unsigned short xs[4] = {(unsigned short)(xr2.x & 0xffff), (unsigned short)(xr2.x >> 16),
                                        (unsigned short)(xr2.y & 0xffff), (unsigned short)(xr2.y >> 16)};
                uint2 pv;
                pv.x = pack2(f2bf(v.x + bias + bf2f(xs[0])), f2bf(v.y + bias + bf2f(xs[1])));
                pv.y = pack2(f2bf(v.z + bias + bf2f(xs[2])), f2bf(v.w + bias + bf2f(xs[3])));
                *(uint2*)((unsigned short*)outv + base) = pv;
            }
        }
        __syncthreads();
    }
}

extern "C" void kernel_launch(void* const* d_in, const int* in_sizes, int n_in,
                              void* d_out, int out_size, void* d_ws, size_t ws_size,
                              hipStream_t stream) {
    const void* x    = d_in[0];
    const void* gnw  = d_in[1];
    const void* gnb  = d_in[2];
    const void* qkvw = d_in[3];
    const void* outw = d_in[4];
    const void* outb = d_in[5];
    char* ws = (char*)d_ws;

    // ---- workspace layout
    unsigned short* xt   = (unsigned short*)(ws);              // 64 MiB, [b][n][c]
    unsigned short* wdst = (unsigned short*)(ws + 67108864);   // 656896 B
    char* sm = ws + 68157440;
    int*    flag    = (int*)(sm);
    float2* gstats  = (float2*)(sm + 64);
    float*  beta    = (float*)(sm + 1024);      // 4*768 f32
    float2* stats   = (float2*)(sm + 16384);    // nb*256 f2 (pass-local)
    float*  gamma   = (float*)(sm + 24576);     // 4*256 f32
    float2* gn_part = (float2*)(sm + 32768);    // 2048 f2
    float*  sim     = (float*)(sm + 65536);     // 4*8*1024 f32
    unsigned short* M  = (unsigned short*)(sm + 262144);  // 4*256*256 bf16
    unsigned short* G2 = (unsigned short*)(sm + 786432);  // 4*256*512 bf16
    const size_t kv_off = 70254592;

    const unsigned short* wq   = wdst;
    const unsigned short* wo   = wdst + 196608;
    const unsigned short* wgnw = wdst + 262144;
    const unsigned short* wgnb = wdst + 262400;
    const unsigned short* wob  = wdst + 262656;
    const unsigned short* wqT  = wdst + 262912;

    int nb = 1;
    if      (ws_size >= kv_off + 4ull * (33554432 + 2097152)) nb = 4;
    else if (ws_size >= kv_off + 2ull * (33554432 + 2097152)) nb = 2;

    unsigned short* kv = (unsigned short*)(ws + kv_off);
    float* partials    = (float*)(ws + kv_off + (size_t)nb * 33554432);

    k_detect <<<dim3(1),    dim3(64),  0, stream>>>((const unsigned int*)x, flag);
    k_cvt_w  <<<dim3(1283), dim3(256), 0, stream>>>(qkvw, outw, gnw, gnb, outb, flag, wdst);
    k_gnsum  <<<dim3(2048), dim3(256), 0, stream>>>(x, flag, gn_part);
    k_gnfinal<<<dim3(16),   dim3(128), 0, stream>>>(gn_part, gstats);
    k_beta   <<<dim3(3072), dim3(64),  0, stream>>>(wq, wgnw, wgnb, gstats, beta);
    k_cvt_t  <<<dim3(8192), dim3(256), 0, stream>>>(x, flag, wgnw, gstats, xt);

    for (int pass = 0; pass < 4; pass += nb) {
        k_gemm1  <<<dim3(1024 * nb), dim3(256), 0, stream>>>(wq, xt, beta, kv, pass);
        k_stats  <<<dim3(256 * nb),  dim3(256), 0, stream>>>(kv, stats);
        k_sim    <<<dim3(512 * nb),  dim3(64),  0, stream>>>(kv, stats, partials);
        k_combine<<<dim3(8 * nb),    dim3(256), 0, stream>>>(partials, sim, pass);
        k_buildM <<<dim3(256 * nb),  dim3(256), 0, stream>>>(wo, sim, beta, wob, M, gamma, pass);
        k_buildG <<<dim3(4 * nb),    dim3(256), 0, stream>>>(M, wqT, G2, pass);
    }
    // GEMM2 for all batches in one launch (xt/G2/gamma persistent).
    k_gemm2<<<dim3(2048), dim3(256), 0, stream>>>(xt, G2, gamma, x, flag, d_out);
}

// Round 4
// 510.293 us; speedup vs baseline: 1.5698x; 1.0196x over previous
//
#include <hip/hip_runtime.h>
#include <cmath>

// AttentionBlock fused pipeline for MI355X (gfx950). Dtype-adaptive:
// probe detects fp32 vs bf16 input; compute runs in bf16 MFMA; epilogue
// honors the real dtype.
//
// B=4, C=256, N=32768, G=4 (64ch/group), NH=8, hd=32.
//
// This revision: double-buffered 2-phase GEMM K-loop. The global_load_lds
// stage for K-tile kt+1 is issued into the idle LDS buffer BEFORE the MFMA
// cluster of tile kt; the trailing __syncthreads (vmcnt(0)+barrier) then
// pays only the residual latency not covered by the MFMA phase. LDS 64KB
// (A0,B0,A1,B1 tiles of 128x64 bf16). Applied to gemm1/gemm2/buildG.

typedef __bf16 bf16x8 __attribute__((ext_vector_type(8)));
typedef float f32x4 __attribute__((ext_vector_type(4)));

union U16 { uint4 u; unsigned short s[8]; bf16x8 v; };

__device__ __forceinline__ float bf2f(unsigned short h) {
    unsigned int u = ((unsigned int)h) << 16;
    return __builtin_bit_cast(float, u);
}
__device__ __forceinline__ unsigned short f2bf(float f) {
    unsigned int u = __builtin_bit_cast(unsigned int, f);
    u = (u + 0x7fffu + ((u >> 16) & 1u)) >> 16;   // RNE
    return (unsigned short)u;
}
__device__ __forceinline__ unsigned int pack2(unsigned short a, unsigned short b) {
    return (unsigned int)a | ((unsigned int)b << 16);
}

// ------------------------------------------------------------- dtype probe
__global__ __launch_bounds__(64) void k_detect(const unsigned int* __restrict__ xr,
                                               int* __restrict__ flag) {
    unsigned int u = xr[threadIdx.x * 997];
    int e = (u >> 7) & 0xFF;
    bool ok = (e >= 100) && (e <= 141);
    unsigned long long m = __ballot(ok);
    if (threadIdx.x == 0) *flag = (__popcll(m) < 32) ? 1 : 0;   // 1 = fp32
}

// --------------------------------------------------- weight convert / copy
// wdst: qkvw[196608] | outw[65536] | gnw[256] | gnb[256] | outb[256] | wqT[65536]
__global__ __launch_bounds__(256) void k_cvt_w(const void* __restrict__ qkvw,
                                               const void* __restrict__ outw,
                                               const void* __restrict__ gnw,
                                               const void* __restrict__ gnb,
                                               const void* __restrict__ outb,
                                               const int* __restrict__ flagp,
                                               unsigned short* __restrict__ wdst) {
    int idx = blockIdx.x * 256 + threadIdx.x;
    if (idx >= 328448) return;
    int f = *flagp;
    const void* src; int off;
    if      (idx < 196608) { src = qkvw; off = idx; }
    else if (idx < 262144) { src = outw; off = idx - 196608; }
    else if (idx < 262400) { src = gnw;  off = idx - 262144; }
    else if (idx < 262656) { src = gnb;  off = idx - 262400; }
    else if (idx < 262912) { src = outb; off = idx - 262656; }
    else {  // wqT[c][d] = qkvw[d][c], q-part only (d<256)
        int i = idx - 262912;
        int c = i >> 8, d = i & 255;
        src = qkvw; off = d * 256 + c;
    }
    wdst[idx] = f ? f2bf(((const float*)src)[off])
                  : ((const unsigned short*)src)[off];
}

// ---------------------------------------------------------------- GN stats
__global__ __launch_bounds__(256) void k_gnsum(const void* __restrict__ xr,
                                               const int* __restrict__ flagp,
                                               float2* __restrict__ gn_part) {
    int t = threadIdx.x, bid = blockIdx.x;
    int grp = bid >> 7, chunk = bid & 127;
    size_t base = (size_t)grp * 2097152 + (size_t)chunk * 16384;
    int f = *flagp;
    float s = 0.f, q = 0.f;
    if (f) {
        const float* p = (const float*)xr + base;
        for (int i = 0; i < 8; i++) {
            float4 a = *(const float4*)(p + i * 2048 + t * 8);
            float4 b = *(const float4*)(p + i * 2048 + t * 8 + 4);
            float v[8] = {a.x, a.y, a.z, a.w, b.x, b.y, b.z, b.w};
#pragma unroll
            for (int j = 0; j < 8; j++) { s += v[j]; q += v[j] * v[j]; }
        }
    } else {
        const unsigned short* p = (const unsigned short*)xr + base;
        for (int i = 0; i < 8; i++) {
            U16 u; u.u = *(const uint4*)(p + i * 2048 + t * 8);
#pragma unroll
            for (int j = 0; j < 8; j++) { float v = bf2f(u.s[j]); s += v; q += v * v; }
        }
    }
#pragma unroll
    for (int off = 32; off > 0; off >>= 1) { s += __shfl_xor(s, off); q += __shfl_xor(q, off); }
    __shared__ float rs[4], rq[4];
    int wave = t >> 6;
    if ((t & 63) == 0) { rs[wave] = s; rq[wave] = q; }
    __syncthreads();
    if (t == 0) gn_part[bid] = make_float2(rs[0] + rs[1] + rs[2] + rs[3],
                                           rq[0] + rq[1] + rq[2] + rq[3]);
}

__global__ __launch_bounds__(128) void k_gnfinal(const float2* __restrict__ gn_part,
                                                 float2* __restrict__ gstats) {
    int bg = blockIdx.x, t = threadIdx.x;
    float2 v = gn_part[bg * 128 + t];
    float s = v.x, q = v.y;
#pragma unroll
    for (int off = 32; off > 0; off >>= 1) { s += __shfl_xor(s, off); q += __shfl_xor(q, off); }
    __shared__ float rs[2], rq[2];
    if ((t & 63) == 0) { rs[t >> 6] = s; rq[t >> 6] = q; }
    __syncthreads();
    if (t == 0) {
        const float inv = 1.0f / 2097152.0f;
        float S = rs[0] + rs[1], Q = rq[0] + rq[1];
        float mean = S * inv;
        float var = Q * inv - mean * mean;
        gstats[bg] = make_float2(mean, rsqrtf(var + 1e-5f));
    }
}

// ---------------------------------------------------------------- beta_b[o]
__global__ __launch_bounds__(64) void k_beta(const unsigned short* __restrict__ wq,
                                             const unsigned short* __restrict__ wgnw,
                                             const unsigned short* __restrict__ wgnb,
                                             const float2* __restrict__ gstats,
                                             float* __restrict__ beta) {
    int bid = blockIdx.x;
    int b = bid / 768, o = bid % 768;
    int t = threadIdx.x, c = t * 4;
    float2 ms = gstats[b * 4 + (c >> 6)];
    uint2 qw = *(const uint2*)(wq + o * 256 + c);
    uint2 gw = *(const uint2*)(wgnw + c);
    uint2 gb = *(const uint2*)(wgnb + c);
    unsigned short qs[4] = {(unsigned short)(qw.x & 0xffff), (unsigned short)(qw.x >> 16),
                            (unsigned short)(qw.y & 0xffff), (unsigned short)(qw.y >> 16)};
    unsigned short wsx[4] = {(unsigned short)(gw.x & 0xffff), (unsigned short)(gw.x >> 16),
                             (unsigned short)(gw.y & 0xffff), (unsigned short)(gw.y >> 16)};
    unsigned short bs[4] = {(unsigned short)(gb.x & 0xffff), (unsigned short)(gb.x >> 16),
                            (unsigned short)(gb.y & 0xffff), (unsigned short)(gb.y >> 16)};
    float bacc = 0.f;
#pragma unroll
    for (int j = 0; j < 4; j++)
        bacc += bf2f(qs[j]) * (bf2f(bs[j]) - ms.x * ms.y * bf2f(wsx[j]));
#pragma unroll
    for (int off = 32; off > 0; off >>= 1) bacc += __shfl_xor(bacc, off);
    if (t == 0) beta[b * 768 + o] = bacc;
}

// --------------------------- convert + transpose + fold GN scale (raw x -> xt)
__global__ __launch_bounds__(256) void k_cvt_t(const void* __restrict__ xr,
                                               const int* __restrict__ flagp,
                                               const unsigned short* __restrict__ wgnw,
                                               const float2* __restrict__ gstats,
                                               unsigned short* __restrict__ xt) {
    int tid = threadIdx.x, bid = blockIdx.x;
    int b = bid >> 11, r2 = bid & 2047, cblk = r2 >> 9, nblk = r2 & 511;
    float rstd = gstats[b * 4 + cblk].y;
    int f = *flagp;
    __shared__ __align__(16) unsigned short T[64 * 80];
    unsigned short tmp[2][8];
#pragma unroll
    for (int i = 0; i < 2; i++) {
        int crow = (tid >> 3) + 32 * i, nch = tid & 7;
        int c = cblk * 64 + crow;
        float sc = bf2f(wgnw[c]) * rstd;
        size_t base = ((size_t)(b * 256 + c)) * 32768 + (size_t)nblk * 64 + nch * 8;
        float v[8];
        if (f) {
            float4 a = *(const float4*)((const float*)xr + base);
            float4 d = *(const float4*)((const float*)xr + base + 4);
            v[0] = a.x; v[1] = a.y; v[2] = a.z; v[3] = a.w;
            v[4] = d.x; v[5] = d.y; v[6] = d.z; v[7] = d.w;
        } else {
            U16 u; u.u = *(const uint4*)((const unsigned short*)xr + base);
#pragma unroll
            for (int j = 0; j < 8; j++) v[j] = bf2f(u.s[j]);
        }
#pragma unroll
        for (int j = 0; j < 8; j++) tmp[i][j] = f2bf(v[j] * sc);
    }
#pragma unroll
    for (int i = 0; i < 2; i++) {
        int crow = (tid >> 3) + 32 * i, nch = tid & 7;
#pragma unroll
        for (int jj = 0; jj < 8; jj++) {
            int j = (jj + tid) & 7;
            T[(nch * 8 + j) * 80 + crow] = tmp[i][j];
        }
    }
    __syncthreads();
#pragma unroll
    for (int i = 0; i < 2; i++) {
        int nrow = (tid >> 3) + 32 * i, cch = tid & 7;
        uint4 v = *(const uint4*)&T[nrow * 80 + cch * 8];
        *(uint4*)(xt + ((size_t)b * 32768 + (size_t)nblk * 64 + nrow) * 256 + cblk * 64 + cch * 8) = v;
    }
}

// ---------------------------------------------------------------- GEMM core
// LDS tile [row][64 bf16], LINEAR layout fed by global_load_lds; the XOR
// chunk swizzle (logical chunk c of row r lives at slot c^(r&7)) is applied
// on the per-lane GLOBAL source address; ds_read applies the same XOR.
__device__ __forceinline__ void stage_tile(const unsigned short* __restrict__ g, int stride,
                                           unsigned short* __restrict__ lds, int tid) {
    int lane = tid & 63, wave = tid >> 6;
    int r8 = lane >> 3, s = lane & 7;
#pragma unroll
    for (int i = 0; i < 4; i++) {
        int row0 = wave * 32 + i * 8;
        int row = row0 + r8;
        const unsigned short* src = g + (size_t)row * stride + ((s ^ (row & 7)) << 3);
        // lane l of the wave writes lds_base + l*16 (HW-linear); src is per-lane.
        __builtin_amdgcn_global_load_lds(
            (__attribute__((address_space(1))) void*)src,
            (__attribute__((address_space(3))) void*)(lds + row0 * 64),
            16, 0, 0);
    }
}

__device__ __forceinline__ void mfma_tile(const unsigned short* __restrict__ ldsA,
                                          const unsigned short* __restrict__ ldsB,
                                          int l15, int quad, int wm, int wn,
                                          f32x4 (&acc)[4][4]) {
#pragma unroll
    for (int ks = 0; ks < 2; ks++) {
        bf16x8 af[4], bv[4];
#pragma unroll
        for (int mi = 0; mi < 4; mi++) {
            int row = wm * 64 + mi * 16 + l15;
            af[mi] = *(const bf16x8*)&ldsA[row * 64 + (((ks * 4 + quad) ^ (row & 7)) * 8)];
        }
#pragma unroll
        for (int ni = 0; ni < 4; ni++) {
            int row = wn * 64 + ni * 16 + l15;
            bv[ni] = *(const bf16x8*)&ldsB[row * 64 + (((ks * 4 + quad) ^ (row & 7)) * 8)];
        }
#pragma unroll
        for (int mi = 0; mi < 4; mi++)
#pragma unroll
            for (int ni = 0; ni < 4; ni++)
                acc[mi][ni] = __builtin_amdgcn_mfma_f32_16x16x32_bf16(af[mi], bv[ni], acc[mi][ni], 0, 0, 0);
    }
}

// Double-buffered pipelined K-loop. lds must hold 4 tiles of 128x64 bf16
// (A0 @0, B0 @8192, A1 @16384, B1 @24576 elems). The stage for kt+1 is
// issued BEFORE the MFMA of kt; __syncthreads (vmcnt0+barrier) at the end
// of each iteration pays only the latency not hidden by the MFMA phase.
template<int KSTEPS, int KAMASK>
__device__ __forceinline__ void gemm_core_db(const unsigned short* __restrict__ A, int strideA,
                                             const unsigned short* __restrict__ B, int strideB,
                                             unsigned short* lds, int tid, f32x4 (&acc)[4][4]) {
    int lane = tid & 63, l15 = lane & 15, quad = lane >> 4;
    int wave = tid >> 6, wm = wave & 1, wn = wave >> 1;
    stage_tile(A, strideA, lds, tid);
    stage_tile(B, strideB, lds + 8192, tid);
    __syncthreads();
#pragma unroll
    for (int kt = 0; kt < KSTEPS; ++kt) {
        unsigned short* cur = lds + (kt & 1) * 16384;
        unsigned short* nxt = lds + (((kt & 1) ^ 1)) * 16384;
        if (kt + 1 < KSTEPS) {
            stage_tile(A + ((kt + 1) & KAMASK) * 64, strideA, nxt, tid);
            stage_tile(B + (kt + 1) * 64, strideB, nxt + 8192, tid);
        }
        mfma_tile(cur, cur + 8192, l15, quad, wm, wn, acc);
        __syncthreads();
    }
}

// GEMM1: kv = wq_kv . xt^T + beta  (K/V rows only; q never materialized)
__global__ __launch_bounds__(256) void k_gemm1(const unsigned short* __restrict__ wq,
                                               const unsigned short* __restrict__ xt,
                                               const float* __restrict__ beta,
                                               unsigned short* __restrict__ kv,
                                               int b0) {
    __shared__ __align__(16) unsigned short ldsbuf[4 * 128 * 64];
    int tid = threadIdx.x, bid = blockIdx.x;
    // XCD-grouped: 4 mblks sharing one xt tile consecutive on one XCD.
    int L = (bid & 7) * ((int)gridDim.x >> 3) + (bid >> 3);
    int mblk = L & 3;
    int t2 = L >> 2;
    int nblk = t2 & 255, bl = t2 >> 8;
    int gb = b0 + bl;
    int o0 = 256 + mblk * 128;           // qkv row index (k/v region)
    size_t n0 = (size_t)nblk * 128;
    const unsigned short* A = wq + (size_t)o0 * 256;
    const unsigned short* B = xt + ((size_t)gb * 32768 + n0) * 256;
    f32x4 acc[4][4] = {};
    gemm_core_db<4, 3>(A, 256, B, 256, ldsbuf, tid, acc);

    int lane = tid & 63, l15 = lane & 15, quad = lane >> 4;
    int wave = tid >> 6, wm = wave & 1, wn = wave >> 1;
    // stage [o][n] bf16 swizzled in LDS, then full-line kv stores
#pragma unroll
    for (int mi = 0; mi < 4; mi++) {
        int o_l = wm * 64 + mi * 16 + quad * 4;
        float4 be = *(const float4*)(beta + gb * 768 + o0 + o_l);
        float bev[4] = {be.x, be.y, be.z, be.w};
#pragma unroll
        for (int ni = 0; ni < 4; ni++) {
            int n_l = wn * 64 + ni * 16 + l15;
            f32x4 v = acc[mi][ni];
#pragma unroll
            for (int r = 0; r < 4; r++) {
                int o_r = o_l + r;
                ldsbuf[(o_r * 128 + n_l) ^ ((o_r & 7) << 3)] = f2bf(v[r] + bev[r]);
            }
        }
    }
    __syncthreads();
    int kv0 = mblk * 128;
#pragma unroll
    for (int p = 0; p < 8; p++) {
        int o_r = p * 16 + (tid >> 4);
        int ch = tid & 15;
        uint4 v = *(const uint4*)&ldsbuf[(o_r * 128 + ch * 8) ^ ((o_r & 7) << 3)];
        *(uint4*)(kv + ((size_t)bl * 512 + kv0 + o_r) * 32768 + n0 + ch * 8) = v;
    }
}

// ------------------------------------------------- softmax row stats (pass-local)
__global__ __launch_bounds__(256) void k_stats(const unsigned short* __restrict__ kv,
                                               float2* __restrict__ stats) {
    int row = blockIdx.x, t = threadIdx.x;
    const unsigned short* p = kv + ((size_t)(row >> 8) * 512 + (row & 255)) * 32768;
    float m = -3.0e38f;
    for (int i = 0; i < 16; i++) {
        U16 u; u.u = *(const uint4*)(p + i * 2048 + t * 8);
#pragma unroll
        for (int j = 0; j < 8; j++) m = fmaxf(m, bf2f(u.s[j]));
    }
#pragma unroll
    for (int off = 32; off > 0; off >>= 1) m = fmaxf(m, __shfl_xor(m, off));
    __shared__ float rm[4], rs[4];
    int wave = t >> 6;
    if ((t & 63) == 0) rm[wave] = m;
    __syncthreads();
    m = fmaxf(fmaxf(rm[0], rm[1]), fmaxf(rm[2], rm[3]));
    float s = 0.f;
    for (int i = 0; i < 16; i++) {
        U16 u; u.u = *(const uint4*)(p + i * 2048 + t * 8);
#pragma unroll
        for (int j = 0; j < 8; j++) s += __expf(bf2f(u.s[j]) - m);
    }
#pragma unroll
    for (int off = 32; off > 0; off >>= 1) s += __shfl_xor(s, off);
    if ((t & 63) == 0) rs[wave] = s;
    __syncthreads();
    if (t == 0) stats[row] = make_float2(m, 1.0f / (rs[0] + rs[1] + rs[2] + rs[3]));
}

// ----------------------------- sim partials (pass-local)
__global__ __launch_bounds__(64) void k_sim(const unsigned short* __restrict__ kv,
                                            const float2* __restrict__ stats,
                                            float* __restrict__ partials) {
    int bid = blockIdx.x;
    int bh = bid >> 6, chunk = bid & 63;
    int b = bh >> 3, h = bh & 7;
    int lane = threadIdx.x, l15 = lane & 15, quad = lane >> 4;
    size_t n0 = (size_t)chunk * 512 + quad * 8;
    float mrow[2], isr[2];
#pragma unroll
    for (int mi = 0; mi < 2; mi++) {
        float2 st = stats[b * 256 + h * 32 + mi * 16 + l15];
        mrow[mi] = st.x; isr[mi] = st.y;
    }
    const unsigned short* kb = kv + ((size_t)b * 512 + h * 32) * 32768;
    const unsigned short* vb = kv + ((size_t)b * 512 + 256 + h * 32) * 32768;
    f32x4 acc[2][2] = {};
    for (int t = 0; t < 16; t++) {
        size_t n = n0 + t * 32;
        bf16x8 af[2], bv[2];
#pragma unroll
        for (int mi = 0; mi < 2; mi++) {
            U16 u; u.u = *(const uint4*)(kb + (size_t)(mi * 16 + l15) * 32768 + n);
            U16 pv;
#pragma unroll
            for (int j = 0; j < 8; j++) pv.s[j] = f2bf(__expf(bf2f(u.s[j]) - mrow[mi]) * isr[mi]);
            af[mi] = pv.v;
        }
#pragma unroll
        for (int ni = 0; ni < 2; ni++) {
            U16 u; u.u = *(const uint4*)(vb + (size_t)(ni * 16 + l15) * 32768 + n);
            bv[ni] = u.v;
        }
#pragma unroll
        for (int mi = 0; mi < 2; mi++)
#pragma unroll
            for (int ni = 0; ni < 2; ni++)
                acc[mi][ni] = __builtin_amdgcn_mfma_f32_16x16x32_bf16(af[mi], bv[ni], acc[mi][ni], 0, 0, 0);
    }
    float* po = partials + (size_t)(bh * 64 + chunk) * 1024;
#pragma unroll
    for (int mi = 0; mi < 2; mi++)
#pragma unroll
        for (int ni = 0; ni < 2; ni++)
#pragma unroll
            for (int rr = 0; rr < 4; rr++)
                po[(mi * 16 + quad * 4 + rr) * 32 + ni * 16 + l15] = acc[mi][ni][rr];
}

__global__ __launch_bounds__(256) void k_combine(const float* __restrict__ partials,
                                                 float* __restrict__ sim, int b0) {
    int bh = blockIdx.x, tid = threadIdx.x;
#pragma unroll
    for (int i = 0; i < 4; i++) {
        float a = 0.f;
        const float* p = partials + (size_t)bh * 65536 + tid + i * 256;
        for (int c = 0; c < 64; c++) a += p[(size_t)c * 1024];
        sim[(size_t)(b0 * 8 + bh) * 1024 + tid + i * 256] = a;
    }
}

// buildM + folded gamma: M[b][o][c] and gamma[b][o] = M.beta_q + out_b
__global__ __launch_bounds__(256) void k_buildM(const unsigned short* __restrict__ wo,
                                                const float* __restrict__ sim,
                                                const float* __restrict__ beta,
                                                const unsigned short* __restrict__ wob,
                                                unsigned short* __restrict__ M,
                                                float* __restrict__ gamma, int b0) {
    int bid = blockIdx.x, tid = threadIdx.x;
    int b = b0 + (bid >> 8), o = bid & 255;
    __shared__ float lw[256];
    __shared__ float ls[8192];
    lw[tid] = bf2f(wo[o * 256 + tid]);
#pragma unroll
    for (int i = 0; i < 32; i++) ls[tid + i * 256] = sim[(size_t)b * 8192 + tid + i * 256];
    __syncthreads();
    int h = tid >> 5, d = tid & 31;
    float a = 0.f;
#pragma unroll
    for (int e = 0; e < 32; e++) {
        int ee = (e + d) & 31;
        a += lw[h * 32 + ee] * ls[h * 1024 + d * 32 + ee];
    }
    unsigned short mh = f2bf(a);
    M[((size_t)b * 256 + o) * 256 + tid] = mh;
    // gamma[b][o] = sum_c M[o][c] * beta_q[b][c]  (+ out_b)
    float g = bf2f(mh) * beta[b * 768 + tid];
#pragma unroll
    for (int off = 32; off > 0; off >>= 1) g += __shfl_xor(g, off);
    __shared__ float rg[4];
    if ((tid & 63) == 0) rg[tid >> 6] = g;
    __syncthreads();
    if (tid == 0) gamma[b * 256 + o] = rg[0] + rg[1] + rg[2] + rg[3] + bf2f(wob[o]);
}

// G2[b][o][0:256] = hi(M.Wq), G2[b][o][256:512] = lo  (row stride 512)
__global__ __launch_bounds__(256) void k_buildG(const unsigned short* __restrict__ M,
                                                const unsigned short* __restrict__ wqT,
                                                unsigned short* __restrict__ G2, int b0) {
    __shared__ __align__(16) unsigned short ldsbuf[4 * 128 * 64];
    int tid = threadIdx.x, bid = blockIdx.x;
    int b = b0 + (bid >> 2), t = bid & 3;
    int o0 = (t >> 1) * 128, c0 = (t & 1) * 128;
    const unsigned short* A = M + (size_t)b * 65536 + (size_t)o0 * 256;   // rows o
    const unsigned short* B = wqT + (size_t)c0 * 256;                     // rows c
    f32x4 acc[4][4] = {};
    gemm_core_db<4, 3>(A, 256, B, 256, ldsbuf, tid, acc);

    int lane = tid & 63, l15 = lane & 15, quad = lane >> 4;
    int wave = tid >> 6, wm = wave & 1, wn = wave >> 1;
#pragma unroll
    for (int mi = 0; mi < 4; mi++) {
        int o_l = o0 + wm * 64 + mi * 16 + quad * 4;
#pragma unroll
        for (int ni = 0; ni < 4; ni++) {
            int c_l = c0 + wn * 64 + ni * 16 + l15;
            f32x4 v = acc[mi][ni];
#pragma unroll
            for (int r = 0; r < 4; r++) {
                float g = v[r];
                unsigned short hi = f2bf(g);
                unsigned short lo = f2bf(g - bf2f(hi));
                size_t rb = (size_t)b * 131072 + (size_t)(o_l + r) * 512 + c_l;
                G2[rb] = hi;
                G2[rb + 256] = lo;
            }
        }
    }
}

// GEMM2 (all batches): out[b][o][n] = xt[n][.] . G2[o][.] + gamma + x  (K=512)
__global__ __launch_bounds__(256) void k_gemm2(const unsigned short* __restrict__ xt,
                                               const unsigned short* __restrict__ G2,
                                               const float* __restrict__ gamma,
                                               const void* __restrict__ xr,
                                               const int* __restrict__ flagp,
                                               void* __restrict__ outv) {
    __shared__ __align__(16) unsigned short ldsbuf[4 * 128 * 64];
    float* ldsF = (float*)ldsbuf;
    int tid = threadIdx.x, bid = blockIdx.x;
    // XCD-grouped: 2 oblks sharing one xt tile consecutive on one XCD.
    int L = (bid & 7) * ((int)gridDim.x >> 3) + (bid >> 3);
    int oblk = L & 1;
    int mblk = (L >> 1) & 255;
    int b = L >> 9;
    size_t n0 = (size_t)mblk * 128;
    int o0 = oblk * 128;
    const unsigned short* A = xt + ((size_t)b * 32768 + n0) * 256;
    const unsigned short* Bg = G2 + (size_t)b * 131072 + (size_t)o0 * 512;
    f32x4 acc[4][4] = {};
    gemm_core_db<8, 3>(A, 256, Bg, 512, ldsbuf, tid, acc);

    int f = *flagp;
    int lane = tid & 63, l15 = lane & 15, quad = lane >> 4;
    int wave = tid >> 6, wm = wave & 1, wn = wave >> 1;
    // acc rows = n-local (mi,quad,reg), cols = o-local (ni,l15).
    // Two half-passes over o: stage fp32 [o_h][n] (32KB) swizzled, then
    // cooperative residual + full-line store in [o][n].
    for (int half = 0; half < 2; half++) {
        if (wn == half) {
#pragma unroll
            for (int mi = 0; mi < 4; mi++) {
#pragma unroll
                for (int ni = 0; ni < 4; ni++) {
                    int o_h = ni * 16 + l15;
                    f32x4 v = acc[mi][ni];
#pragma unroll
                    for (int r = 0; r < 4; r++) {
                        int n_l = wm * 64 + mi * 16 + quad * 4 + r;
                        ldsF[(o_h * 128 + n_l) ^ ((o_h & 15) << 2)] = v[r];
                    }
                }
            }
        }
        __syncthreads();
#pragma unroll
        for (int p = 0; p < 8; p++) {
            int o_h = p * 8 + (tid >> 5);
            int ch = tid & 31;
            float4 v = *(const float4*)&ldsF[(o_h * 128 + ch * 4) ^ ((o_h & 15) << 2)];
            int o = o0 + half * 64 + o_h;
            float bias = gamma[b * 256 + o];
            size_t base = ((size_t)b * 256 + o) * 32768 + n0 + ch * 4;
            if (f) {
                float4 xv = *(const float4*)((const float*)xr + base);
                float4 ov = make_float4(v.x + bias + xv.x, v.y + bias + xv.y,
                                        v.z + bias + xv.z, v.w + bias + xv.w);
                *(float4*)((float*)outv + base) = ov;
            } else {
                uint2 xr2 = *(const uint2*)((const unsigned short*)xr + base);
                unsigned short xs[4] = {(unsigned short)(xr2.x & 0xffff), (unsigned short)(xr2.x >> 16),
                                        (unsigned short)(xr2.y & 0xffff), (unsigned short)(xr2.y >> 16)};
                uint2 pv;
                pv.x = pack2(f2bf(v.x + bias + bf2f(xs[0])), f2bf(v.y + bias + bf2f(xs[1])));
                pv.y = pack2(f2bf(v.z + bias + bf2f(xs[2])), f2bf(v.w + bias + bf2f(xs[3])));
                *(uint2*)((unsigned short*)outv + base) = pv;
            }
        }
        __syncthreads();
    }
}

extern "C" void kernel_launch(void* const* d_in, const int* in_sizes, int n_in,
                              void* d_out, int out_size, void* d_ws, size_t ws_size,
                              hipStream_t stream) {
    const void* x    = d_in[0];
    const void* gnw  = d_in[1];
    const void* gnb  = d_in[2];
    const void* qkvw = d_in[3];
    const void* outw = d_in[4];
    const void* outb = d_in[5];
    char* ws = (char*)d_ws;

    // ---- workspace layout
    unsigned short* xt   = (unsigned short*)(ws);              // 64 MiB, [b][n][c]
    unsigned short* wdst = (unsigned short*)(ws + 67108864);   // 656896 B
    char* sm = ws + 68157440;
    int*    flag    = (int*)(sm);
    float2* gstats  = (float2*)(sm + 64);
    float*  beta    = (float*)(sm + 1024);      // 4*768 f32
    float2* stats   = (float2*)(sm + 16384);    // nb*256 f2 (pass-local)
    float*  gamma   = (float*)(sm + 24576);     // 4*256 f32
    float2* gn_part = (float2*)(sm + 32768);    // 2048 f2
    float*  sim     = (float*)(sm + 65536);     // 4*8*1024 f32
    unsigned short* M  = (unsigned short*)(sm + 262144);  // 4*256*256 bf16
    unsigned short* G2 = (unsigned short*)(sm + 786432);  // 4*256*512 bf16
    const size_t kv_off = 70254592;

    const unsigned short* wq   = wdst;
    const unsigned short* wo   = wdst + 196608;
    const unsigned short* wgnw = wdst + 262144;
    const unsigned short* wgnb = wdst + 262400;
    const unsigned short* wob  = wdst + 262656;
    const unsigned short* wqT  = wdst + 262912;

    int nb = 1;
    if      (ws_size >= kv_off + 4ull * (33554432 + 2097152)) nb = 4;
    else if (ws_size >= kv_off + 2ull * (33554432 + 2097152)) nb = 2;

    unsigned short* kv = (unsigned short*)(ws + kv_off);
    float* partials    = (float*)(ws + kv_off + (size_t)nb * 33554432);

    k_detect <<<dim3(1),    dim3(64),  0, stream>>>((const unsigned int*)x, flag);
    k_cvt_w  <<<dim3(1283), dim3(256), 0, stream>>>(qkvw, outw, gnw, gnb, outb, flag, wdst);
    k_gnsum  <<<dim3(2048), dim3(256), 0, stream>>>(x, flag, gn_part);
    k_gnfinal<<<dim3(16),   dim3(128), 0, stream>>>(gn_part, gstats);
    k_beta   <<<dim3(3072), dim3(64),  0, stream>>>(wq, wgnw, wgnb, gstats, beta);
    k_cvt_t  <<<dim3(8192), dim3(256), 0, stream>>>(x, flag, wgnw, gstats, xt);

    for (int pass = 0; pass < 4; pass += nb) {
        k_gemm1  <<<dim3(1024 * nb), dim3(256), 0, stream>>>(wq, xt, beta, kv, pass);
        k_stats  <<<dim3(256 * nb),  dim3(256), 0, stream>>>(kv, stats);
        k_sim    <<<dim3(512 * nb),  dim3(64),  0, stream>>>(kv, stats, partials);
        k_combine<<<dim3(8 * nb),    dim3(256), 0, stream>>>(partials, sim, pass);
        k_buildM <<<dim3(256 * nb),  dim3(256), 0, stream>>>(wo, sim, beta, wob, M, gamma, pass);
        k_buildG <<<dim3(4 * nb),    dim3(256), 0, stream>>>(M, wqT, G2, pass);
    }
    // GEMM2 for all batches in one launch (xt/G2/gamma persistent).
    k_gemm2<<<dim3(2048), dim3(256), 0, stream>>>(xt, G2, gamma, x, flag, d_out);
}